// Round 1
// baseline (196.619 us; speedup 1.0000x reference)
//
#include <hip/hip_runtime.h>
#include <math.h>

// Problem constants
constexpr int BATCH = 2048;   // B
constexpr int NSTEP = 2;      // STEP
constexpr int ROWS  = NSTEP * BATCH; // 4096
constexpr int HID   = 512;
constexpr int NACT  = 8;

__device__ __forceinline__ float gelu_f(float x) {
    // exact gelu: x * 0.5 * (1 + erf(x/sqrt(2)))
    return 0.5f * x * (1.0f + erff(x * 0.70710678118654752f));
}

// ---------------------------------------------------------------------------
// K0: compute time embedding (cur_t = 49) and fold it + b_in into a combined
// bias: bias_comb[n] = b_in[n] + sum_k temb[k] * W_in[14+k][n]
// ---------------------------------------------------------------------------
__global__ void k_setup(const float* __restrict__ W_in, const float* __restrict__ b_in,
                        float* __restrict__ bias_comb, float temb_mult, float cur_t) {
    __shared__ float temb[512];
    int t = threadIdx.x;
    if (t < 256) {
        float div = expf((float)(2 * t) * temb_mult);
        temb[2 * t]     = sinf(cur_t * div);
        temb[2 * t + 1] = cosf(cur_t * div);
    }
    __syncthreads();
    float acc = b_in[t];
    for (int k = 0; k < 512; ++k)
        acc += temb[k] * W_in[(14 + k) * HID + t];
    bias_comb[t] = acc;
}

// ---------------------------------------------------------------------------
// K1: input layer. y = gelu([x_pre | nz] @ W_in[0:14] + bias_comb)
// one thread per output element (ROWS*HID)
// ---------------------------------------------------------------------------
__global__ __launch_bounds__(256) void k_layer_in(
        const float* __restrict__ x_pre, const float* __restrict__ noise,
        const float* __restrict__ W_in, const float* __restrict__ bias_comb,
        float* __restrict__ Y) {
    int idx = blockIdx.x * 256 + threadIdx.x;
    int r = idx >> 9;          // row 0..4095
    int n = idx & 511;         // col
    int s = r >> 11;           // step
    int b = r & 2047;          // batch
    float acc = bias_comb[n];
    const float* xp = &x_pre[b * 6];
#pragma unroll
    for (int j = 0; j < 6; ++j)
        acc += xp[j] * W_in[j * HID + n];
    const float* nzp = &noise[(s * BATCH + b) * NACT];
#pragma unroll
    for (int j = 0; j < 8; ++j)
        acc += nzp[j] * W_in[(6 + j) * HID + n];
    Y[idx] = gelu_f(acc);
}

// ---------------------------------------------------------------------------
// K2..K5: Y = gelu(X @ W + b), X: ROWS x 512, W: 512 x 512 (row-major)
// BM=BN=64, BK=16, 256 threads, 4x4 micro-tile per thread
// ---------------------------------------------------------------------------
constexpr int BM = 64, BN = 64, BK = 16;

__global__ __launch_bounds__(256) void k_gemm_gelu(
        const float* __restrict__ X, const float* __restrict__ W,
        const float* __restrict__ bias, float* __restrict__ Y) {
    __shared__ float As[BK][BM];   // A transposed: As[k][m]
    __shared__ float Bs[BK][BN];

    int m0 = blockIdx.x * BM;
    int n0 = blockIdx.y * BN;
    int tid = threadIdx.x;
    int tx = tid & 15;          // n direction
    int ty = tid >> 4;          // m direction

    // loader indices
    int la_r = tid >> 2;            // 0..63 : row in A tile
    int la_c = (tid & 3) * 4;       // 0,4,8,12 : col in A tile
    int lb_r = tid >> 4;            // 0..15 : k row in B tile
    int lb_c = (tid & 15) * 4;      // col in B tile

    float acc[4][4] = {};

    for (int k0 = 0; k0 < HID; k0 += BK) {
        float4 av = *(const float4*)&X[(m0 + la_r) * HID + k0 + la_c];
        As[la_c + 0][la_r] = av.x;
        As[la_c + 1][la_r] = av.y;
        As[la_c + 2][la_r] = av.z;
        As[la_c + 3][la_r] = av.w;
        float4 bv = *(const float4*)&W[(k0 + lb_r) * HID + n0 + lb_c];
        *(float4*)&Bs[lb_r][lb_c] = bv;
        __syncthreads();
#pragma unroll
        for (int k = 0; k < BK; ++k) {
            float4 a = *(const float4*)&As[k][ty * 4];
            float4 bvv = *(const float4*)&Bs[k][tx * 4];
            float am[4] = {a.x, a.y, a.z, a.w};
            float bm[4] = {bvv.x, bvv.y, bvv.z, bvv.w};
#pragma unroll
            for (int i = 0; i < 4; ++i)
#pragma unroll
                for (int j = 0; j < 4; ++j)
                    acc[i][j] += am[i] * bm[j];
        }
        __syncthreads();
    }

#pragma unroll
    for (int i = 0; i < 4; ++i) {
        int row = m0 + ty * 4 + i;
        float4 o;
        float b0 = bias[n0 + tx * 4 + 0];
        float b1 = bias[n0 + tx * 4 + 1];
        float b2 = bias[n0 + tx * 4 + 2];
        float b3 = bias[n0 + tx * 4 + 3];
        o.x = gelu_f(acc[i][0] + b0);
        o.y = gelu_f(acc[i][1] + b1);
        o.z = gelu_f(acc[i][2] + b2);
        o.w = gelu_f(acc[i][3] + b3);
        *(float4*)&Y[row * HID + n0 + tx * 4] = o;
    }
}

// ---------------------------------------------------------------------------
// K6: output layer + DDIM combine + tanh + FK + distance errors
// one wave (64 lanes) per row
// ---------------------------------------------------------------------------
__device__ void mat4mul(float C[4][4], const float A[4][4], const float Bm[4][4]) {
#pragma unroll
    for (int i = 0; i < 4; ++i)
#pragma unroll
        for (int j = 0; j < 4; ++j) {
            float s = A[i][0] * Bm[0][j];
            s += A[i][1] * Bm[1][j];
            s += A[i][2] * Bm[2][j];
            s += A[i][3] * Bm[3][j];
            C[i][j] = s;
        }
}

__global__ __launch_bounds__(256) void k_out_fk(
        const float* __restrict__ Yin, const float* __restrict__ W_out,
        const float* __restrict__ b_out, const float* __restrict__ noise,
        const float* __restrict__ x_pre,
        float* __restrict__ joints, float* __restrict__ errs,
        float c1, float c2, float c3) {
    int wid = blockIdx.x * 4 + (threadIdx.x >> 6);
    int lane = threadIdx.x & 63;
    int r = wid;
    int s = r >> 11;
    int b = r & 2047;

    float acc[8] = {0, 0, 0, 0, 0, 0, 0, 0};
    const float* yrow = &Yin[r * HID];
    for (int k = lane; k < HID; k += 64) {
        float yv = yrow[k];
        const float* wr = &W_out[k * NACT];
#pragma unroll
        for (int n = 0; n < 8; ++n) acc[n] += yv * wr[n];
    }
#pragma unroll
    for (int n = 0; n < 8; ++n) {
#pragma unroll
        for (int off = 32; off > 0; off >>= 1)
            acc[n] += __shfl_down(acc[n], off, 64);
    }

    if (lane == 0) {
        const float HIf[8] = {
            (float)(35.0 * M_PI / 180.0), (float)(-60.0 * M_PI / 180.0), 3.94f,
            (float)(155.0 * M_PI / 180.0), (float)(-55.0 * M_PI / 180.0),
            (float)M_PI, (float)(5.0 * M_PI / 180.0), 3.71f};
        const float LOf[8] = {
            (float)(-35.0 * M_PI / 180.0), (float)(-155.0 * M_PI / 180.0), 2.59f,
            (float)(60.0 * M_PI / 180.0), (float)(-125.0 * M_PI / 180.0),
            (float)(-M_PI), (float)(-90.0 * M_PI / 180.0), 2.5f};
        const float* nzp = &noise[(s * BATCH + b) * NACT];
        float jq[8];
#pragma unroll
        for (int n = 0; n < 8; ++n) {
            float out = acc[n] + b_out[n];
            float z = c1 * nzp[n] + c2 * out + c3 * nzp[n];
            float jn = (tanhf(z * 0.1f) + 1.0f) * 0.5f;
            jq[n] = jn * (HIf[n] - LOf[n]) + LOf[n];
            joints[(s * BATCH + b) * NACT + n] = jq[n];
        }
        // forward kinematics
        const float a_[8]  = {0.0f, 0.16f, 0.07f, 0.0f, 0.1334f, 0.0f, 0.15f, 0.3625f};
        const float ca_[8] = {1.f, 0.f, 0.f, 0.f, 0.f, 0.f, 0.f, 0.f};
        const float sa_[8] = {0.f, -1.f, -1.f, 1.f, -1.f, -1.f, 1.f, -1.f};
        float d_[8] = {0.0f, 0.0f, jq[2], 0.0f, -0.1316f, 1.0105f, 0.52f, jq[7]};
        float th[8] = {jq[0], jq[1], 0.0f, jq[3], jq[4], jq[5], jq[6], 0.0f};

        float T[4][4], M[4][4], Tn[4][4];
#pragma unroll
        for (int j = 0; j < 8; ++j) {
            float ct = cosf(th[j]);
            float st = sinf(th[j]);
            M[0][0] = ct;            M[0][1] = -st;           M[0][2] = 0.0f;     M[0][3] = a_[j];
            M[1][0] = st * ca_[j];   M[1][1] = ct * ca_[j];   M[1][2] = -sa_[j];  M[1][3] = -sa_[j] * d_[j];
            M[2][0] = st * sa_[j];   M[2][1] = ct * sa_[j];   M[2][2] = ca_[j];   M[2][3] = ca_[j] * d_[j];
            M[3][0] = 0.0f;          M[3][1] = 0.0f;          M[3][2] = 0.0f;     M[3][3] = 1.0f;
            if (j == 0) {
#pragma unroll
                for (int i = 0; i < 4; ++i)
#pragma unroll
                    for (int c = 0; c < 4; ++c) T[i][c] = M[i][c];
            } else {
                mat4mul(Tn, T, M);
#pragma unroll
                for (int i = 0; i < 4; ++i)
#pragma unroll
                    for (int c = 0; c < 4; ++c) T[i][c] = Tn[i][c];
            }
        }
        float e1x = T[0][2] * 3.75f;
        float e1y = T[1][2] * 3.75f;
        float e1z = T[2][2] * 3.75f;
        float pose[6];
        pose[0] = T[0][3];
        pose[1] = T[1][3];
        pose[2] = T[2][3] + 1.702f;
        pose[3] = e1x + T[0][3];
        pose[4] = e1y + T[1][3];
        pose[5] = e1z + T[2][3] + 1.702f;
        const float* xp = &x_pre[b * 6];
        float dx0 = 100.0f * pose[0] - xp[0];
        float dx1 = 100.0f * pose[1] - xp[1];
        float dx2 = 100.0f * pose[2] - xp[2];
        float dx3 = 100.0f * pose[3] - xp[3];
        float dx4 = 100.0f * pose[4] - xp[4];
        float dx5 = 100.0f * pose[5] - xp[5];
        float dist0 = sqrtf(dx0 * dx0 + dx1 * dx1 + dx2 * dx2);
        float dist1 = sqrtf(dx3 * dx3 + dx4 * dx4 + dx5 * dx5);
        errs[s * BATCH + b] = dist0 + dist1;
    }
}

// ---------------------------------------------------------------------------
// K7: argmin over the two steps + gather best joints
// ---------------------------------------------------------------------------
__global__ void k_select(const float* __restrict__ joints, const float* __restrict__ errs,
                         float* __restrict__ out) {
    int b = blockIdx.x * 256 + threadIdx.x;
    if (b >= BATCH) return;
    float e0 = errs[b];
    float e1 = errs[BATCH + b];
    int s = (e1 < e0) ? 1 : 0;   // argmin: first index wins ties
    const float* src = &joints[(s * BATCH + b) * NACT];
#pragma unroll
    for (int n = 0; n < 8; ++n) out[b * NACT + n] = src[n];
}

// ---------------------------------------------------------------------------
extern "C" void kernel_launch(void* const* d_in, const int* in_sizes, int n_in,
                              void* d_out, int out_size, void* d_ws, size_t ws_size,
                              hipStream_t stream) {
    const float* x_pre = (const float*)d_in[0];
    const float* noise = (const float*)d_in[1];
    const float* W_in  = (const float*)d_in[2];
    const float* b_in  = (const float*)d_in[3];
    const float* W1    = (const float*)d_in[4];
    const float* b1    = (const float*)d_in[5];
    const float* W2    = (const float*)d_in[6];
    const float* b2    = (const float*)d_in[7];
    const float* W3    = (const float*)d_in[8];
    const float* b3    = (const float*)d_in[9];
    const float* W4    = (const float*)d_in[10];
    const float* b4    = (const float*)d_in[11];
    const float* W_out = (const float*)d_in[12];
    const float* b_out = (const float*)d_in[13];

    float* wsf = (float*)d_ws;
    float* bias_comb = wsf;                      // 512
    float* joints    = wsf + 512;                // 2*2048*8 = 32768
    float* errs      = joints + 2 * BATCH * 8;   // 4096
    float* Ya        = wsf + 40960;              // ROWS*HID
    float* Yb        = Ya + ROWS * HID;          // ROWS*HID

    // DDIM coefficients for the LAST step (the only one that matters:
    // z is overwritten every iteration in the reference, nz never updated).
    // cur = 49, ab_prev = 1
    double ab_c = exp(-0.1 * 50.0 / 1000.0 - 0.5 * (10.0 - 0.1) * 2500.0 / 1.0e6);
    float c1 = (float)sqrt(1.0 / ab_c);
    float c2 = (float)(-sqrt((1.0 - ab_c) / ab_c));
    float c3 = (float)sqrt(1.0 - ab_c);
    float temb_mult = (float)(-log(10000.0) / 512.0);

    k_setup<<<1, 512, 0, stream>>>(W_in, b_in, bias_comb, temb_mult, 49.0f);
    k_layer_in<<<ROWS * HID / 256, 256, 0, stream>>>(x_pre, noise, W_in, bias_comb, Ya);
    dim3 g(ROWS / BM, HID / BN);
    k_gemm_gelu<<<g, 256, 0, stream>>>(Ya, W1, b1, Yb);
    k_gemm_gelu<<<g, 256, 0, stream>>>(Yb, W2, b2, Ya);
    k_gemm_gelu<<<g, 256, 0, stream>>>(Ya, W3, b3, Yb);
    k_gemm_gelu<<<g, 256, 0, stream>>>(Yb, W4, b4, Ya);
    k_out_fk<<<ROWS / 4, 256, 0, stream>>>(Ya, W_out, b_out, noise, x_pre,
                                           joints, errs, c1, c2, c3);
    k_select<<<(BATCH + 255) / 256, 256, 0, stream>>>(joints, errs, (float*)d_out);
}

// Round 2
// 124.537 us; speedup vs baseline: 1.5788x; 1.5788x over previous
//
#include <hip/hip_runtime.h>
#include <math.h>

typedef __bf16 bf16x8 __attribute__((ext_vector_type(8)));
typedef float f32x4 __attribute__((ext_vector_type(4)));
typedef unsigned short u16;
typedef unsigned int u32;

constexpr int BATCH = 2048;
constexpr int NSTEP = 2;
constexpr int ROWS  = NSTEP * BATCH; // 4096
constexpr int HID   = 512;
constexpr int NACT  = 8;

__device__ __forceinline__ float gelu_f(float x) {
    return 0.5f * x * (1.0f + erff(x * 0.70710678118654752f));
}
__device__ __forceinline__ u16 f2bf(float f) {
    u32 u = __float_as_uint(f);
    return (u16)((u + 0x7FFFu + ((u >> 16) & 1u)) >> 16);
}
__device__ __forceinline__ float bf2f(u16 h) {
    return __uint_as_float(((u32)h) << 16);
}

// ===========================================================================
// NEW MFMA PATH
// ===========================================================================

// K0a: split-K partial sums of temb @ W_in[14:526]
__global__ void k_setup1(const float* __restrict__ W_in, float* __restrict__ partials) {
    __shared__ float temb[32];
    int bz = blockIdx.x, t = threadIdx.x;
    if (t < 32) {
        int k = bz * 32 + t;
        int p = k >> 1;
        float div = expf((float)(2 * p) * (-9.210340371976184f / 512.0f));
        temb[t] = (k & 1) ? cosf(49.0f * div) : sinf(49.0f * div);
    }
    __syncthreads();
    float acc = 0.f;
    for (int kk = 0; kk < 32; ++kk)
        acc += temb[kk] * W_in[(size_t)(14 + bz * 32 + kk) * HID + t];
    partials[bz * HID + t] = acc;
}

// K0b: reduce partials + b_in
__global__ void k_setup2(const float* __restrict__ b_in, const float* __restrict__ partials,
                         float* __restrict__ bias_comb) {
    int t = threadIdx.x;
    float a = b_in[t];
    for (int b = 0; b < 16; ++b) a += partials[b * HID + t];
    bias_comb[t] = a;
}

// K0c: transpose + hi/lo-split all 4 hidden weight matrices.
// wt layout per layer l: hi plane [n][k] at l*524288, lo plane at +262144 (u16 units)
__global__ __launch_bounds__(256) void k_prep_wt(
        const float* __restrict__ W1, const float* __restrict__ W2,
        const float* __restrict__ W3, const float* __restrict__ W4,
        u16* __restrict__ wt) {
    __shared__ float tile[32][33];
    const float* Ws[4] = {W1, W2, W3, W4};
    const float* W = Ws[blockIdx.z];
    u16* wh = wt + (size_t)blockIdx.z * 524288;
    u16* wl = wh + 262144;
    int kt = blockIdx.x * 32, nt = blockIdx.y * 32, t = threadIdx.x;
    int c = t & 31, r = t >> 5;
#pragma unroll
    for (int p = 0; p < 4; ++p)
        tile[r + p * 8][c] = W[(size_t)(kt + r + p * 8) * HID + nt + c];
    __syncthreads();
#pragma unroll
    for (int p = 0; p < 4; ++p) {
        int nl = r + p * 8, kl = c;
        float v = tile[kl][nl];
        u16 h = f2bf(v);
        u16 l2 = f2bf(v - bf2f(h));
        size_t o = (size_t)(nt + nl) * HID + kt + kl;
        wh[o] = h;
        wl[o] = l2;
    }
}

// K1: input layer -> bf16 hi/lo planes
__global__ __launch_bounds__(256) void k_layer_in2(
        const float* __restrict__ x_pre, const float* __restrict__ noise,
        const float* __restrict__ W_in, const float* __restrict__ bias_comb,
        u16* __restrict__ Yh, u16* __restrict__ Yl) {
    int idx = blockIdx.x * 256 + threadIdx.x;
    int r = idx >> 9, n = idx & 511, s = r >> 11, b = r & 2047;
    float acc = bias_comb[n];
    const float* xp = &x_pre[b * 6];
#pragma unroll
    for (int j = 0; j < 6; ++j) acc += xp[j] * W_in[j * HID + n];
    const float* nz = &noise[(s * BATCH + b) * NACT];
#pragma unroll
    for (int j = 0; j < 8; ++j) acc += nz[j] * W_in[(6 + j) * HID + n];
    float g = gelu_f(acc);
    u16 h = f2bf(g);
    Yh[idx] = h;
    Yl[idx] = f2bf(g - bf2f(h));
}

// K2..K5: Y = gelu(A @ W + b) via split-bf16 3-pass MFMA.
// A as hi/lo planes [M][512]; W^T as hi/lo planes [n][k].
// BM=BN=64, 4 waves, each wave a 32x32 tile; BK=32 double-buffered.
__global__ __launch_bounds__(256) void k_gemm_mfma(
        const u16* __restrict__ Ah, const u16* __restrict__ Al,
        const u16* __restrict__ Wh, const u16* __restrict__ Wl,
        const float* __restrict__ bias,
        u16* __restrict__ Yh, u16* __restrict__ Yl) {
    __shared__ __align__(16) u16 lds[2][4][4][512]; // [buf][plane Ah,Al,Wh,Wl][grp][16rows x 32k]
    int tid = threadIdx.x, lane = tid & 63, w = tid >> 6;
    int wm = w >> 1, wn = w & 1;
    int m0 = blockIdx.x * 64, n0 = blockIdx.y * 64;
    int l15 = lane & 15, k8 = (lane >> 4) * 8;

    const u16* gp0 = Ah + (size_t)(m0 + w * 16 + l15) * HID + k8;
    const u16* gp1 = Al + (size_t)(m0 + w * 16 + l15) * HID + k8;
    const u16* gp2 = Wh + (size_t)(n0 + w * 16 + l15) * HID + k8;
    const u16* gp3 = Wl + (size_t)(n0 + w * 16 + l15) * HID + k8;

    f32x4 zero = {0.f, 0.f, 0.f, 0.f};
    f32x4 acc[2][2] = {{zero, zero}, {zero, zero}};

    auto stage = [&](int c, int bb) {
        int off = c * 32;
        __builtin_amdgcn_global_load_lds((const __attribute__((address_space(1))) void*)(gp0 + off),
            (__attribute__((address_space(3))) void*)&lds[bb][0][w][0], 16, 0, 0);
        __builtin_amdgcn_global_load_lds((const __attribute__((address_space(1))) void*)(gp1 + off),
            (__attribute__((address_space(3))) void*)&lds[bb][1][w][0], 16, 0, 0);
        __builtin_amdgcn_global_load_lds((const __attribute__((address_space(1))) void*)(gp2 + off),
            (__attribute__((address_space(3))) void*)&lds[bb][2][w][0], 16, 0, 0);
        __builtin_amdgcn_global_load_lds((const __attribute__((address_space(1))) void*)(gp3 + off),
            (__attribute__((address_space(3))) void*)&lds[bb][3][w][0], 16, 0, 0);
    };

    stage(0, 0);
    for (int c = 0; c < 16; ++c) {
        int bb = c & 1;
        __syncthreads();
        if (c < 15) stage(c + 1, bb ^ 1);
        bf16x8 ah[2], al[2], bh[2], bl[2];
#pragma unroll
        for (int i = 0; i < 2; ++i) {
            ah[i] = *(const bf16x8*)&lds[bb][0][wm * 2 + i][lane * 8];
            al[i] = *(const bf16x8*)&lds[bb][1][wm * 2 + i][lane * 8];
            bh[i] = *(const bf16x8*)&lds[bb][2][wn * 2 + i][lane * 8];
            bl[i] = *(const bf16x8*)&lds[bb][3][wn * 2 + i][lane * 8];
        }
#pragma unroll
        for (int i = 0; i < 2; ++i)
#pragma unroll
            for (int j = 0; j < 2; ++j) {
                acc[i][j] = __builtin_amdgcn_mfma_f32_16x16x32_bf16(ah[i], bh[j], acc[i][j], 0, 0, 0);
                acc[i][j] = __builtin_amdgcn_mfma_f32_16x16x32_bf16(ah[i], bl[j], acc[i][j], 0, 0, 0);
                acc[i][j] = __builtin_amdgcn_mfma_f32_16x16x32_bf16(al[i], bh[j], acc[i][j], 0, 0, 0);
            }
    }

#pragma unroll
    for (int i = 0; i < 2; ++i) {
        int row0 = m0 + wm * 32 + i * 16 + (lane >> 4) * 4;
#pragma unroll
        for (int j = 0; j < 2; ++j) {
            int col = n0 + wn * 32 + j * 16 + l15;
            float bia = bias[col];
#pragma unroll
            for (int r2 = 0; r2 < 4; ++r2) {
                float g = gelu_f(acc[i][j][r2] + bia);
                u16 h = f2bf(g);
                size_t o = (size_t)(row0 + r2) * HID + col;
                Yh[o] = h;
                Yl[o] = f2bf(g - bf2f(h));
            }
        }
    }
}

// K6 helpers
__device__ void mat4mul(float C[4][4], const float A[4][4], const float Bm[4][4]) {
#pragma unroll
    for (int i = 0; i < 4; ++i)
#pragma unroll
        for (int j = 0; j < 4; ++j) {
            float s = A[i][0] * Bm[0][j];
            s += A[i][1] * Bm[1][j];
            s += A[i][2] * Bm[2][j];
            s += A[i][3] * Bm[3][j];
            C[i][j] = s;
        }
}

__device__ __forceinline__ void fk_tail(int s, int b, const float acc[8],
        const float* __restrict__ b_out, const float* __restrict__ noise,
        const float* __restrict__ x_pre, float* __restrict__ joints,
        float* __restrict__ errs, float c1, float c2, float c3) {
    const float HIf[8] = {
        (float)(35.0 * M_PI / 180.0), (float)(-60.0 * M_PI / 180.0), 3.94f,
        (float)(155.0 * M_PI / 180.0), (float)(-55.0 * M_PI / 180.0),
        (float)M_PI, (float)(5.0 * M_PI / 180.0), 3.71f};
    const float LOf[8] = {
        (float)(-35.0 * M_PI / 180.0), (float)(-155.0 * M_PI / 180.0), 2.59f,
        (float)(60.0 * M_PI / 180.0), (float)(-125.0 * M_PI / 180.0),
        (float)(-M_PI), (float)(-90.0 * M_PI / 180.0), 2.5f};
    const float* nzp = &noise[(s * BATCH + b) * NACT];
    float jq[8];
#pragma unroll
    for (int n = 0; n < 8; ++n) {
        float out = acc[n] + b_out[n];
        float z = c1 * nzp[n] + c2 * out + c3 * nzp[n];
        float jn = (tanhf(z * 0.1f) + 1.0f) * 0.5f;
        jq[n] = jn * (HIf[n] - LOf[n]) + LOf[n];
        joints[(s * BATCH + b) * NACT + n] = jq[n];
    }
    const float a_[8]  = {0.0f, 0.16f, 0.07f, 0.0f, 0.1334f, 0.0f, 0.15f, 0.3625f};
    const float ca_[8] = {1.f, 0.f, 0.f, 0.f, 0.f, 0.f, 0.f, 0.f};
    const float sa_[8] = {0.f, -1.f, -1.f, 1.f, -1.f, -1.f, 1.f, -1.f};
    float d_[8] = {0.0f, 0.0f, jq[2], 0.0f, -0.1316f, 1.0105f, 0.52f, jq[7]};
    float th[8] = {jq[0], jq[1], 0.0f, jq[3], jq[4], jq[5], jq[6], 0.0f};

    float T[4][4], M[4][4], Tn[4][4];
#pragma unroll
    for (int j = 0; j < 8; ++j) {
        float ct = cosf(th[j]);
        float st = sinf(th[j]);
        M[0][0] = ct;          M[0][1] = -st;         M[0][2] = 0.0f;    M[0][3] = a_[j];
        M[1][0] = st * ca_[j]; M[1][1] = ct * ca_[j]; M[1][2] = -sa_[j]; M[1][3] = -sa_[j] * d_[j];
        M[2][0] = st * sa_[j]; M[2][1] = ct * sa_[j]; M[2][2] = ca_[j];  M[2][3] = ca_[j] * d_[j];
        M[3][0] = 0.0f;        M[3][1] = 0.0f;        M[3][2] = 0.0f;    M[3][3] = 1.0f;
        if (j == 0) {
#pragma unroll
            for (int i = 0; i < 4; ++i)
#pragma unroll
                for (int c = 0; c < 4; ++c) T[i][c] = M[i][c];
        } else {
            mat4mul(Tn, T, M);
#pragma unroll
            for (int i = 0; i < 4; ++i)
#pragma unroll
                for (int c = 0; c < 4; ++c) T[i][c] = Tn[i][c];
        }
    }
    float e1x = T[0][2] * 3.75f;
    float e1y = T[1][2] * 3.75f;
    float e1z = T[2][2] * 3.75f;
    float pose[6];
    pose[0] = T[0][3];
    pose[1] = T[1][3];
    pose[2] = T[2][3] + 1.702f;
    pose[3] = e1x + T[0][3];
    pose[4] = e1y + T[1][3];
    pose[5] = e1z + T[2][3] + 1.702f;
    const float* xp = &x_pre[b * 6];
    float dx0 = 100.0f * pose[0] - xp[0];
    float dx1 = 100.0f * pose[1] - xp[1];
    float dx2 = 100.0f * pose[2] - xp[2];
    float dx3 = 100.0f * pose[3] - xp[3];
    float dx4 = 100.0f * pose[4] - xp[4];
    float dx5 = 100.0f * pose[5] - xp[5];
    float dist0 = sqrtf(dx0 * dx0 + dx1 * dx1 + dx2 * dx2);
    float dist1 = sqrtf(dx3 * dx3 + dx4 * dx4 + dx5 * dx5);
    errs[s * BATCH + b] = dist0 + dist1;
}

// K6: output layer (hi/lo input) + DDIM + tanh + FK + errors
__global__ __launch_bounds__(256) void k_out_fk2(
        const u16* __restrict__ Yh, const u16* __restrict__ Yl,
        const float* __restrict__ W_out, const float* __restrict__ b_out,
        const float* __restrict__ noise, const float* __restrict__ x_pre,
        float* __restrict__ joints, float* __restrict__ errs,
        float c1, float c2, float c3) {
    int wid = blockIdx.x * 4 + (threadIdx.x >> 6);
    int lane = threadIdx.x & 63;
    int s = wid >> 11, b = wid & 2047;

    float acc[8] = {0, 0, 0, 0, 0, 0, 0, 0};
    const u16* yh = &Yh[(size_t)wid * HID];
    const u16* yl = &Yl[(size_t)wid * HID];
#pragma unroll
    for (int it = 0; it < 8; ++it) {
        int k = lane + it * 64;
        float y = bf2f(yh[k]) + bf2f(yl[k]);
        float4 w0 = ((const float4*)&W_out[k * NACT])[0];
        float4 w1 = ((const float4*)&W_out[k * NACT])[1];
        acc[0] += y * w0.x; acc[1] += y * w0.y; acc[2] += y * w0.z; acc[3] += y * w0.w;
        acc[4] += y * w1.x; acc[5] += y * w1.y; acc[6] += y * w1.z; acc[7] += y * w1.w;
    }
#pragma unroll
    for (int n = 0; n < 8; ++n) {
#pragma unroll
        for (int off = 32; off > 0; off >>= 1)
            acc[n] += __shfl_down(acc[n], off, 64);
    }
    if (lane == 0)
        fk_tail(s, b, acc, b_out, noise, x_pre, joints, errs, c1, c2, c3);
}

// K7: argmin over the two steps + gather
__global__ void k_select(const float* __restrict__ joints, const float* __restrict__ errs,
                         float* __restrict__ out) {
    int b = blockIdx.x * 256 + threadIdx.x;
    if (b >= BATCH) return;
    float e0 = errs[b];
    float e1 = errs[BATCH + b];
    int s = (e1 < e0) ? 1 : 0;
    const float* src = &joints[(s * BATCH + b) * NACT];
#pragma unroll
    for (int n = 0; n < 8; ++n) out[b * NACT + n] = src[n];
}

// ===========================================================================
// FALLBACK FP32 PATH (round-1, known-good) — used if ws_size is too small
// ===========================================================================
__global__ void k_setup_old(const float* __restrict__ W_in, const float* __restrict__ b_in,
                            float* __restrict__ bias_comb, float temb_mult, float cur_t) {
    __shared__ float temb[512];
    int t = threadIdx.x;
    if (t < 256) {
        float div = expf((float)(2 * t) * temb_mult);
        temb[2 * t]     = sinf(cur_t * div);
        temb[2 * t + 1] = cosf(cur_t * div);
    }
    __syncthreads();
    float acc = b_in[t];
    for (int k = 0; k < 512; ++k)
        acc += temb[k] * W_in[(14 + k) * HID + t];
    bias_comb[t] = acc;
}

__global__ __launch_bounds__(256) void k_layer_in_old(
        const float* __restrict__ x_pre, const float* __restrict__ noise,
        const float* __restrict__ W_in, const float* __restrict__ bias_comb,
        float* __restrict__ Y) {
    int idx = blockIdx.x * 256 + threadIdx.x;
    int r = idx >> 9, n = idx & 511, s = r >> 11, b = r & 2047;
    float acc = bias_comb[n];
    const float* xp = &x_pre[b * 6];
#pragma unroll
    for (int j = 0; j < 6; ++j) acc += xp[j] * W_in[j * HID + n];
    const float* nzp = &noise[(s * BATCH + b) * NACT];
#pragma unroll
    for (int j = 0; j < 8; ++j) acc += nzp[j] * W_in[(6 + j) * HID + n];
    Y[idx] = gelu_f(acc);
}

constexpr int OBM = 64, OBN = 64, OBK = 16;
__global__ __launch_bounds__(256) void k_gemm_gelu_old(
        const float* __restrict__ X, const float* __restrict__ W,
        const float* __restrict__ bias, float* __restrict__ Y) {
    __shared__ float As[OBK][OBM];
    __shared__ float Bs[OBK][OBN];
    int m0 = blockIdx.x * OBM, n0 = blockIdx.y * OBN;
    int tid = threadIdx.x;
    int tx = tid & 15, ty = tid >> 4;
    int la_r = tid >> 2, la_c = (tid & 3) * 4;
    int lb_r = tid >> 4, lb_c = (tid & 15) * 4;
    float acc[4][4] = {};
    for (int k0 = 0; k0 < HID; k0 += OBK) {
        float4 av = *(const float4*)&X[(m0 + la_r) * HID + k0 + la_c];
        As[la_c + 0][la_r] = av.x;
        As[la_c + 1][la_r] = av.y;
        As[la_c + 2][la_r] = av.z;
        As[la_c + 3][la_r] = av.w;
        float4 bv = *(const float4*)&W[(k0 + lb_r) * HID + n0 + lb_c];
        *(float4*)&Bs[lb_r][lb_c] = bv;
        __syncthreads();
#pragma unroll
        for (int k = 0; k < OBK; ++k) {
            float4 a = *(const float4*)&As[k][ty * 4];
            float4 bvv = *(const float4*)&Bs[k][tx * 4];
            float am[4] = {a.x, a.y, a.z, a.w};
            float bm[4] = {bvv.x, bvv.y, bvv.z, bvv.w};
#pragma unroll
            for (int i = 0; i < 4; ++i)
#pragma unroll
                for (int j = 0; j < 4; ++j)
                    acc[i][j] += am[i] * bm[j];
        }
        __syncthreads();
    }
#pragma unroll
    for (int i = 0; i < 4; ++i) {
        int row = m0 + ty * 4 + i;
        float4 o;
        o.x = gelu_f(acc[i][0] + bias[n0 + tx * 4 + 0]);
        o.y = gelu_f(acc[i][1] + bias[n0 + tx * 4 + 1]);
        o.z = gelu_f(acc[i][2] + bias[n0 + tx * 4 + 2]);
        o.w = gelu_f(acc[i][3] + bias[n0 + tx * 4 + 3]);
        *(float4*)&Y[row * HID + n0 + tx * 4] = o;
    }
}

__global__ __launch_bounds__(256) void k_out_fk_old(
        const float* __restrict__ Yin, const float* __restrict__ W_out,
        const float* __restrict__ b_out, const float* __restrict__ noise,
        const float* __restrict__ x_pre,
        float* __restrict__ joints, float* __restrict__ errs,
        float c1, float c2, float c3) {
    int wid = blockIdx.x * 4 + (threadIdx.x >> 6);
    int lane = threadIdx.x & 63;
    int s = wid >> 11, b = wid & 2047;
    float acc[8] = {0, 0, 0, 0, 0, 0, 0, 0};
    const float* yrow = &Yin[(size_t)wid * HID];
#pragma unroll
    for (int it = 0; it < 8; ++it) {
        int k = lane + it * 64;
        float yv = yrow[k];
        float4 w0 = ((const float4*)&W_out[k * NACT])[0];
        float4 w1 = ((const float4*)&W_out[k * NACT])[1];
        acc[0] += yv * w0.x; acc[1] += yv * w0.y; acc[2] += yv * w0.z; acc[3] += yv * w0.w;
        acc[4] += yv * w1.x; acc[5] += yv * w1.y; acc[6] += yv * w1.z; acc[7] += yv * w1.w;
    }
#pragma unroll
    for (int n = 0; n < 8; ++n) {
#pragma unroll
        for (int off = 32; off > 0; off >>= 1)
            acc[n] += __shfl_down(acc[n], off, 64);
    }
    if (lane == 0)
        fk_tail(s, b, acc, b_out, noise, x_pre, joints, errs, c1, c2, c3);
}

// ===========================================================================
extern "C" void kernel_launch(void* const* d_in, const int* in_sizes, int n_in,
                              void* d_out, int out_size, void* d_ws, size_t ws_size,
                              hipStream_t stream) {
    const float* x_pre = (const float*)d_in[0];
    const float* noise = (const float*)d_in[1];
    const float* W_in  = (const float*)d_in[2];
    const float* b_in  = (const float*)d_in[3];
    const float* W1    = (const float*)d_in[4];
    const float* b1    = (const float*)d_in[5];
    const float* W2    = (const float*)d_in[6];
    const float* b2    = (const float*)d_in[7];
    const float* W3    = (const float*)d_in[8];
    const float* b3    = (const float*)d_in[9];
    const float* W4    = (const float*)d_in[10];
    const float* b4    = (const float*)d_in[11];
    const float* W_out = (const float*)d_in[12];
    const float* b_out = (const float*)d_in[13];

    // DDIM last-step coefficients (only the last iteration matters: z is
    // overwritten every loop iteration in the reference, nz never updated).
    double ab_c = exp(-0.1 * 50.0 / 1000.0 - 0.5 * (10.0 - 0.1) * 2500.0 / 1.0e6);
    float c1 = (float)sqrt(1.0 / ab_c);
    float c2 = (float)(-sqrt((1.0 - ab_c) / ab_c));
    float c3 = (float)sqrt(1.0 - ab_c);

    const size_t NEED = 21153792; // 16MB act planes + 4MB wt + small
    if (ws_size >= NEED) {
        char* base = (char*)d_ws;
        u16* Ah = (u16*)base;                 // 4096x512
        u16* Al = Ah + 2097152;
        u16* Bh = Al + 2097152;
        u16* Bl = Bh + 2097152;
        u16* wt = (u16*)(base + 16777216);    // 4 layers x (hi,lo) [n][k]
        float* joints    = (float*)(base + 16777216 + 4194304);
        float* errs      = joints + 32768;
        float* bias_comb = errs + 4096;
        float* partials  = bias_comb + 512;

        k_setup1<<<16, 512, 0, stream>>>(W_in, partials);
        k_setup2<<<1, 512, 0, stream>>>(b_in, partials, bias_comb);
        k_prep_wt<<<dim3(16, 16, 4), 256, 0, stream>>>(W1, W2, W3, W4, wt);
        k_layer_in2<<<ROWS * HID / 256, 256, 0, stream>>>(x_pre, noise, W_in, bias_comb, Ah, Al);
        dim3 g(ROWS / 64, HID / 64);
        k_gemm_mfma<<<g, 256, 0, stream>>>(Ah, Al, wt + 0 * 524288, wt + 0 * 524288 + 262144, b1, Bh, Bl);
        k_gemm_mfma<<<g, 256, 0, stream>>>(Bh, Bl, wt + 1 * 524288, wt + 1 * 524288 + 262144, b2, Ah, Al);
        k_gemm_mfma<<<g, 256, 0, stream>>>(Ah, Al, wt + 2 * 524288, wt + 2 * 524288 + 262144, b3, Bh, Bl);
        k_gemm_mfma<<<g, 256, 0, stream>>>(Bh, Bl, wt + 3 * 524288, wt + 3 * 524288 + 262144, b4, Ah, Al);
        k_out_fk2<<<ROWS / 4, 256, 0, stream>>>(Ah, Al, W_out, b_out, noise, x_pre,
                                                joints, errs, c1, c2, c3);
        k_select<<<(BATCH + 255) / 256, 256, 0, stream>>>(joints, errs, (float*)d_out);
    } else {
        // fallback: round-1 fp32 pipeline
        float* wsf = (float*)d_ws;
        float* bias_comb = wsf;
        float* joints    = wsf + 512;
        float* errs      = joints + 2 * BATCH * 8;
        float* Ya        = wsf + 40960;
        float* Yb        = Ya + ROWS * HID;
        float temb_mult = (float)(-log(10000.0) / 512.0);

        k_setup_old<<<1, 512, 0, stream>>>(W_in, b_in, bias_comb, temb_mult, 49.0f);
        k_layer_in_old<<<ROWS * HID / 256, 256, 0, stream>>>(x_pre, noise, W_in, bias_comb, Ya);
        dim3 g(ROWS / OBM, HID / OBN);
        k_gemm_gelu_old<<<g, 256, 0, stream>>>(Ya, W1, b1, Yb);
        k_gemm_gelu_old<<<g, 256, 0, stream>>>(Yb, W2, b2, Ya);
        k_gemm_gelu_old<<<g, 256, 0, stream>>>(Ya, W3, b3, Yb);
        k_gemm_gelu_old<<<g, 256, 0, stream>>>(Yb, W4, b4, Ya);
        k_out_fk_old<<<ROWS / 4, 256, 0, stream>>>(Ya, W_out, b_out, noise, x_pre,
                                                   joints, errs, c1, c2, c3);
        k_select<<<(BATCH + 255) / 256, 256, 0, stream>>>(joints, errs, (float*)d_out);
    }
}